// Round 7
// baseline (1551.957 us; speedup 1.0000x reference)
//
#include <hip/hip_runtime.h>
#include <hip/hip_bf16.h>

#define FEATSZ 2048
#define HIDSZ  1024
#define ATTSZ  512
#define BATCH  64
#define FEATN  512

typedef float  f32x4  __attribute__((ext_vector_type(4)));
typedef __bf16 bf16x8 __attribute__((ext_vector_type(8)));

__device__ __forceinline__ unsigned short f2bf(float f) {
    union { float f; unsigned int u; } x; x.f = f;
    unsigned int u = x.u;
    return (unsigned short)((u + 0x7fffu + ((u >> 16) & 1u)) >> 16);
}

// ---------------- K0a: h = key @ wh_w.T + wh_b  (64 x 512) ----------------
__global__ void k_h(const float* __restrict__ key, const float* __restrict__ wh_w,
                    const float* __restrict__ wh_b, float* __restrict__ h) {
    const int b = blockIdx.y;
    const int ac = blockIdx.x;
    const int t = threadIdx.x;         // 256
    const int lane = t & 63, wv = t >> 6;
    float k16[16];
    const float* kb = key + b * HIDSZ;
#pragma unroll
    for (int j = 0; j < 16; ++j) k16[j] = kb[lane + 64 * j];
#pragma unroll 1
    for (int i = 0; i < 16; ++i) {
        int a = ac * 64 + wv * 16 + i;
        const float* wr = wh_w + (size_t)a * HIDSZ;
        float s = 0.f;
#pragma unroll
        for (int j = 0; j < 16; ++j) s += k16[j] * wr[lane + 64 * j];
#pragma unroll
        for (int d = 32; d; d >>= 1) s += __shfl_xor(s, d);
        if (lane == 0) h[b * ATTSZ + a] = s + wh_b[a];
    }
}

// ------- K0b: convert wv_w (512x2048 f32) -> bf16 in MFMA-fragment order -------
// frag (kk, CF) = 1024B at (kk*32+CF)*1024; lane l holds 16B (8 bf16) at +l*16.
__global__ void k_wvcvt(const float* __restrict__ wv_w, unsigned short* __restrict__ wvb) {
    int idx = blockIdx.x * 256 + threadIdx.x;       // < 512*2048
    int a = idx >> 11, k = idx & 2047;
    int CF = a >> 4, c = a & 15, ks = k >> 5, kin = k & 31;
    int lane = c + ((kin >> 3) << 4);
    int dst = ((ks * 32 + CF) * 64 + lane) * 8 + (kin & 7);
    wvb[dst] = f2bf(wv_w[idx]);
}

// ---------------- K1: fused GEMM(feats, wv^T) + tanh·wa -> scores ----------------
// No-barrier K-loop. 512 blocks (2/CU -> 16 free-running waves/CU), 8 waves.
// Block = 64 rows x 512 cols; wave = 64 rows x 64 cols (4 CF frags, disjoint B).
// A frags DIRECT from global (16 full 128B lines per instr; L1 dedups the 8-wave
// redundancy); B from L2-resident frag-ordered wvb. Hand-unrolled x2 pipeline
// with NAMED buffers (static indexing only): loads at iter k consumed at k+2.
__global__ __launch_bounds__(512, 4) void k_scores(
        const float* __restrict__ feats, const unsigned short* __restrict__ wvb,
        const float* __restrict__ h, const float* __restrict__ wv_b,
        const float* __restrict__ wa, float* __restrict__ scores) {
    __shared__ float scp[8][64];
    const int t = threadIdx.x, lane = t & 63, w = t >> 6;
    const int m0 = blockIdx.x * 64, b = blockIdx.x >> 3;

    // A: lane covers row m0 + m*16 + (lane&15), k = kk*32 + (lane>>4)*8 + [0..8)
    const float* gA = feats + (size_t)(m0 + (lane & 15)) * FEATSZ + ((lane >> 4) * 8);
    // B: frag (kk, w*4+cf) at wvb + (kk*32 + w*4 + cf)*512 + lane*8
    const unsigned short* wb = wvb + (size_t)(w * 4) * 512 + lane * 8;

    f32x4 P0[4][2], P1[4][2];      // fp32 A pending (named parities)
    bf16x8 B0[4], B1[4], R[4];     // B ping-pong, A ready (bf16)
    f32x4 acc[4][4];
#pragma unroll
    for (int m = 0; m < 4; ++m)
#pragma unroll
        for (int cf = 0; cf < 4; ++cf) acc[m][cf] = (f32x4)0.0f;

    auto issueA = [&](f32x4 (&P)[4][2], int kk) {
#pragma unroll
        for (int m = 0; m < 4; ++m) {
            const float* p = gA + (size_t)(m * 16) * FEATSZ + kk * 32;
            P[m][0] = *(const f32x4*)p;
            P[m][1] = *(const f32x4*)(p + 4);
        }
    };
    auto issueB = [&](bf16x8 (&B)[4], int kk) {
#pragma unroll
        for (int cf = 0; cf < 4; ++cf)
            B[cf] = *(const bf16x8*)(wb + (size_t)(kk * 32 + cf) * 512);
    };
    auto cvtR = [&](f32x4 (&P)[4][2]) {
#pragma unroll
        for (int m = 0; m < 4; ++m) {
            f32x4 x = P[m][0], y = P[m][1];
            bf16x8 af;
            af[0] = (__bf16)x[0]; af[1] = (__bf16)x[1]; af[2] = (__bf16)x[2]; af[3] = (__bf16)x[3];
            af[4] = (__bf16)y[0]; af[5] = (__bf16)y[1]; af[6] = (__bf16)y[2]; af[7] = (__bf16)y[3];
            R[m] = af;
        }
    };
    auto mfma4 = [&](bf16x8 (&B)[4]) {
        __builtin_amdgcn_s_setprio(1);
#pragma unroll
        for (int m = 0; m < 4; ++m)
#pragma unroll
            for (int cf = 0; cf < 4; ++cf)
                acc[m][cf] = __builtin_amdgcn_mfma_f32_16x16x32_bf16(R[m], B[cf], acc[m][cf], 0, 0, 0);
        __builtin_amdgcn_s_setprio(0);
    };

    // ---- prologue
    issueA(P0, 0);
    issueA(P1, 1);
    issueB(B0, 0);
    cvtR(P0);                       // waits kk=0 A only

#pragma unroll 1
    for (int kk2 = 0; kk2 < 32; ++kk2) {
        const int kk = kk2 * 2;
        // even step: consume R(kk), B0(kk)
        issueB(B1, kk + 1);
        if (kk2 < 31) issueA(P0, kk + 2);
        mfma4(B0);
        cvtR(P1);                   // kk+1 (issued one full iter ago)
        // odd step: consume R(kk+1), B1(kk+1)
        if (kk2 < 31) { issueB(B0, kk + 2); issueA(P1, kk + 3); }
        mfma4(B1);
        if (kk2 < 31) cvtR(P0);     // kk+2
    }

    // ---- epilogue: score[row] = sum_a tanh(v + h + wv_b) * wa  (wave cols w*64..)
    const int c16 = lane & 15, q4 = lane >> 4;
    float hreg[4], wreg[4];
#pragma unroll
    for (int cf = 0; cf < 4; ++cf) {
        int a = w * 64 + cf * 16 + c16;
        hreg[cf] = h[b * ATTSZ + a] + wv_b[a];
        wreg[cf] = wa[a];
    }
    float pv[4][4];
#pragma unroll
    for (int m = 0; m < 4; ++m)
#pragma unroll
        for (int j = 0; j < 4; ++j) pv[m][j] = 0.f;
#pragma unroll
    for (int m = 0; m < 4; ++m)
#pragma unroll
        for (int cf = 0; cf < 4; ++cf)
#pragma unroll
            for (int j = 0; j < 4; ++j)
                pv[m][j] += tanhf(acc[m][cf][j] + hreg[cf]) * wreg[cf];
#pragma unroll
    for (int m = 0; m < 4; ++m)
#pragma unroll
        for (int j = 0; j < 4; ++j) {
            float v = pv[m][j];
            v += __shfl_xor(v, 1); v += __shfl_xor(v, 2);
            v += __shfl_xor(v, 4); v += __shfl_xor(v, 8);
            pv[m][j] = v;
        }
    if (c16 == 0) {
#pragma unroll
        for (int m = 0; m < 4; ++m)
#pragma unroll
            for (int j = 0; j < 4; ++j)
                scp[w][m * 16 + q4 * 4 + j] = pv[m][j];
    }
    __syncthreads();
    if (t < 64) {
        float s = 0.f;
#pragma unroll
        for (int ww = 0; ww < 8; ++ww) s += scp[ww][t];
        scores[m0 + t] = s;
    }
}

// ---------------- K2: softmax over N=512 per batch ----------------
__global__ void k_softmax(const float* __restrict__ scores, float* __restrict__ alpha) {
    __shared__ float red[16];
    const int b = blockIdx.x, t = threadIdx.x;     // 512 threads
    const int lane = t & 63, w = t >> 6;
    float s = scores[b * FEATN + t];
    float m = s;
#pragma unroll
    for (int d = 32; d; d >>= 1) m = fmaxf(m, __shfl_xor(m, d));
    if (lane == 0) red[w] = m;
    __syncthreads();
    if (t == 0) {
        float mm = red[0];
        for (int i = 1; i < 8; ++i) mm = fmaxf(mm, red[i]);
        red[8] = mm;
    }
    __syncthreads();
    float e = __expf(s - red[8]);
    float sum = e;
#pragma unroll
    for (int d = 32; d; d >>= 1) sum += __shfl_xor(sum, d);
    if (lane == 0) red[w] = sum;
    __syncthreads();
    if (t == 0) {
        float ss = 0.f;
        for (int i = 0; i < 8; ++i) ss += red[i];
        red[9] = 1.0f / ss;
    }
    __syncthreads();
    alpha[b * FEATN + t] = e * red[9];
}

// ---------------- K3a: partial att_feats over n-slices ----------------
__global__ void k_att_part(const float* __restrict__ feats, const float* __restrict__ alpha,
                           float* __restrict__ part) {
    const int b = blockIdx.x, fc = blockIdx.y, ns = blockIdx.z, t = threadIdx.x;
    const int f0 = fc * 1024 + t * 4;
    const float* fp = feats + (size_t)(b * FEATN + ns * 128) * FEATSZ + f0;
    const float* al = alpha + b * FEATN + ns * 128;
    float4 acc = {0.f, 0.f, 0.f, 0.f};
#pragma unroll 4
    for (int i = 0; i < 128; ++i) {
        float a = al[i];
        float4 v = *(const float4*)(fp + (size_t)i * FEATSZ);
        acc.x += a * v.x; acc.y += a * v.y; acc.z += a * v.z; acc.w += a * v.w;
    }
    *(float4*)(part + ((size_t)ns * BATCH + b) * FEATSZ + f0) = acc;
}

// ---------------- K3b: reduce 4 partials -> att_feats ----------------
__global__ void k_att_red(const float* __restrict__ part, float* __restrict__ out) {
    const int idx = (blockIdx.x * 256 + threadIdx.x) * 4;   // < 131072
    float4 s = *(const float4*)(part + idx);
#pragma unroll
    for (int z = 1; z < 4; ++z) {
        float4 v = *(const float4*)(part + (size_t)z * (BATCH * FEATSZ) + idx);
        s.x += v.x; s.y += v.y; s.z += v.z; s.w += v.w;
    }
    *(float4*)(out + idx) = s;
}

extern "C" void kernel_launch(void* const* d_in, const int* in_sizes, int n_in,
                              void* d_out, int out_size, void* d_ws, size_t ws_size,
                              hipStream_t stream) {
    const float* feats = (const float*)d_in[0];
    const float* key   = (const float*)d_in[1];
    const float* wh_w  = (const float*)d_in[2];
    const float* wh_b  = (const float*)d_in[3];
    const float* wv_w  = (const float*)d_in[4];
    const float* wv_b  = (const float*)d_in[5];
    const float* wa_w  = (const float*)d_in[6];

    float* out_att   = (float*)d_out;                 // 64*2048
    float* out_alpha = out_att + BATCH * FEATSZ;      // 64*512

    char* ws = (char*)d_ws;
    float* h            = (float*)(ws);               // 128 KB
    float* scores       = (float*)(ws + 131072);      // 128 KB
    unsigned short* wvb = (unsigned short*)(ws + 262144);  // 2 MB
    float* part         = (float*)(ws + 262144);      // 2 MB (reuses wvb after K1)

    hipLaunchKernelGGL(k_h,        dim3(8, 64),    dim3(256), 0, stream, key, wh_w, wh_b, h);
    hipLaunchKernelGGL(k_wvcvt,    dim3(4096),     dim3(256), 0, stream, wv_w, wvb);
    hipLaunchKernelGGL(k_scores,   dim3(512),      dim3(512), 0, stream, feats, wvb, h, wv_b, wa_w, scores);
    hipLaunchKernelGGL(k_softmax,  dim3(64),       dim3(512), 0, stream, scores, out_alpha);
    hipLaunchKernelGGL(k_att_part, dim3(64, 2, 4), dim3(256), 0, stream, feats, out_alpha, part);
    hipLaunchKernelGGL(k_att_red,  dim3(128),      dim3(256), 0, stream, part, out_att);
}

// Round 8
// 165.374 us; speedup vs baseline: 9.3845x; 9.3845x over previous
//
#include <hip/hip_runtime.h>
#include <hip/hip_bf16.h>

#define FEATSZ 2048
#define HIDSZ  1024
#define ATTSZ  512
#define BATCH  64
#define FEATN  512

typedef float  f32x4  __attribute__((ext_vector_type(4)));
typedef __bf16 bf16x8 __attribute__((ext_vector_type(8)));

__device__ __forceinline__ unsigned short f2bf(float f) {
    union { float f; unsigned int u; } x; x.f = f;
    unsigned int u = x.u;
    return (unsigned short)((u + 0x7fffu + ((u >> 16) & 1u)) >> 16);
}

// ---------------- K0a: h = key @ wh_w.T + wh_b  (64 x 512) ----------------
__global__ void k_h(const float* __restrict__ key, const float* __restrict__ wh_w,
                    const float* __restrict__ wh_b, float* __restrict__ h) {
    const int b = blockIdx.y;
    const int ac = blockIdx.x;
    const int t = threadIdx.x;         // 256
    const int lane = t & 63, wv = t >> 6;
    float k16[16];
    const float* kb = key + b * HIDSZ;
#pragma unroll
    for (int j = 0; j < 16; ++j) k16[j] = kb[lane + 64 * j];
#pragma unroll 1
    for (int i = 0; i < 16; ++i) {
        int a = ac * 64 + wv * 16 + i;
        const float* wr = wh_w + (size_t)a * HIDSZ;
        float s = 0.f;
#pragma unroll
        for (int j = 0; j < 16; ++j) s += k16[j] * wr[lane + 64 * j];
#pragma unroll
        for (int d = 32; d; d >>= 1) s += __shfl_xor(s, d);
        if (lane == 0) h[b * ATTSZ + a] = s + wh_b[a];
    }
}

// ------- K0b: convert wv_w (512x2048 f32) -> bf16 in MFMA-fragment order -------
// frag (kk, CF) = 1024B at (kk*32+CF)*1024; lane l holds 16B (8 bf16) at +l*16.
__global__ void k_wvcvt(const float* __restrict__ wv_w, unsigned short* __restrict__ wvb) {
    int idx = blockIdx.x * 256 + threadIdx.x;       // < 512*2048
    int a = idx >> 11, k = idx & 2047;
    int CF = a >> 4, c = a & 15, ks = k >> 5, kin = k & 31;
    int lane = c + ((kin >> 3) << 4);
    int dst = ((ks * 32 + CF) * 64 + lane) * 8 + (kin & 7);
    wvb[dst] = f2bf(wv_w[idx]);
}

// ---------------- K1: fused GEMM(feats, wv^T) + tanh·wa -> scores ----------------
// R3 structure (best: 157us) + T4 counted-vmcnt pipeline:
// 256 blocks (1/CU), 8 waves, Mtile=128, BK=32, 64 kiters.
// A fp32 via global_load_lds into 4 x 16KB XOR-swizzled LDS bufs, staged 2 AHEAD.
// Raw s_barrier + s_waitcnt vmcnt(4) per kiter (prefetches NEVER drained).
// B frags disjoint per wave from L2-resident wvb, 1-kiter ping-pong.
__global__ __launch_bounds__(512, 2) void k_scores(
        const float* __restrict__ feats, const unsigned short* __restrict__ wvb,
        const float* __restrict__ h, const float* __restrict__ wv_b,
        const float* __restrict__ wa, float* __restrict__ scores) {
    __shared__ __align__(16) char smem[4][16384];   // A bufs: [128 rows][32 k] f32 swizzled
    const int t = threadIdx.x;
    const int lane = t & 63, w = t >> 6;
    const int m0 = blockIdx.x * 128;
    const int b = blockIdx.x >> 2;                  // 4 m-blocks per batch

    // ---- A staging: tile = 128 rows x 32 k f32 = 16KB = 1024 x 16B chunks.
    // chunk q: row r=q>>3, slot cs=q&7 holds logical k-chunk c = cs^(r&7).
    const char* fbase = (const char*)feats;
    unsigned int goff[2], ldst[2];
#pragma unroll
    for (int s = 0; s < 2; ++s) {
        int q = w * 128 + s * 64 + lane;
        int r = q >> 3, c = (q & 7) ^ ((q >> 3) & 7);
        goff[s] = (unsigned int)(((m0 + r) * 2048 + c * 4) * 4);
        ldst[s] = (unsigned int)((w * 128 + s * 64) * 16);   // wave-uniform base
    }
    auto stage = [&](int buf, int j) {
#pragma unroll
        for (int s = 0; s < 2; ++s)
            __builtin_amdgcn_global_load_lds(
                (const __attribute__((address_space(1))) void*)(fbase + goff[s] + j * 128),
                (__attribute__((address_space(3))) void*)(&smem[buf][0] + ldst[s]),
                16, 0, 0);
    };

    // ---- B frags (disjoint per wave): frag kk covers cols w*4+cf
    const unsigned short* wb = wvb + lane * 8;
    bf16x8 BA[4], BB[4];
    auto loadBA = [&](int kk) {
#pragma unroll
        for (int cf = 0; cf < 4; ++cf)
            BA[cf] = *(const bf16x8*)(wb + (size_t)(kk * 32 + w * 4 + cf) * 512);
    };
    auto loadBB = [&](int kk) {
#pragma unroll
        for (int cf = 0; cf < 4; ++cf)
            BB[cf] = *(const bf16x8*)(wb + (size_t)(kk * 32 + w * 4 + cf) * 512);
    };

    // ---- swizzled A read offsets: row = m*16+(lane&15), chunk = kq2{,+1} ^ (row&7)
    const int sw = lane & 7, kq2 = (lane >> 4) * 2;
    const int off0 = (lane & 15) * 128 + ((kq2    ) ^ sw) * 16;
    const int off1 = (lane & 15) * 128 + ((kq2 | 1) ^ sw) * 16;

    f32x4 acc[8][4];
#pragma unroll
    for (int m = 0; m < 8; ++m)
#pragma unroll
        for (int cf = 0; cf < 4; ++cf) acc[m][cf] = (f32x4)0.0f;

    auto domfma = [&](const char* ab, bf16x8 (&B)[4]) {
#pragma unroll
        for (int m = 0; m < 8; ++m) {
            f32x4 fa = *(const f32x4*)__builtin_assume_aligned(ab + m * 2048 + off0, 16);
            f32x4 fb = *(const f32x4*)__builtin_assume_aligned(ab + m * 2048 + off1, 16);
            bf16x8 af;
            af[0] = (__bf16)fa[0]; af[1] = (__bf16)fa[1]; af[2] = (__bf16)fa[2]; af[3] = (__bf16)fa[3];
            af[4] = (__bf16)fb[0]; af[5] = (__bf16)fb[1]; af[6] = (__bf16)fb[2]; af[7] = (__bf16)fb[3];
#pragma unroll
            for (int cf = 0; cf < 4; ++cf)
                acc[m][cf] = __builtin_amdgcn_mfma_f32_16x16x32_bf16(af, B[cf], acc[m][cf], 0, 0, 0);
        }
    };

    // ---- prologue: stage j=0,1 ; B kk=0 -> BA. Ensure own st(0) landed, barrier.
    stage(0, 0);
    stage(1, 1);
    loadBA(0);
    asm volatile("s_waitcnt vmcnt(6)" ::: "memory");   // st(0) done; st(1)+BA in flight
    __builtin_amdgcn_s_barrier();
    __builtin_amdgcn_sched_barrier(0);

#pragma unroll 4
    for (int j = 0; j < 64; ++j) {
        const int buf = j & 3;
        // issue next-kiter B (ping-pong) FIRST, then 2-ahead stage
        if ((j & 1) == 0) { if (j < 63) loadBB(j + 1); }
        else             { if (j < 63) loadBA(j + 1); }
        if (j < 62) stage((j + 2) & 3, j + 2);
        __builtin_amdgcn_sched_barrier(0);
        // compute on buf j (ds_reads safe: own st(j) proven landed before prev barrier;
        // cross-wave visibility via prev s_barrier)
        if ((j & 1) == 0) domfma(&smem[buf][0], BA);
        else              domfma(&smem[buf][0], BB);
        __builtin_amdgcn_sched_barrier(0);
        // own st(j+1) done when outstanding <= 4 (next-B 4 and/or st(j+2) 2 remain)
        asm volatile("s_waitcnt vmcnt(4)" ::: "memory");
        __builtin_amdgcn_s_barrier();
        __builtin_amdgcn_sched_barrier(0);
    }

    // ---- epilogue: p[row] = sum_a tanh(acc + h[b,a] + wv_b[a]) * wa[a]
    const int c16 = lane & 15, q4 = lane >> 4;
    float hreg[4], wreg[4];
#pragma unroll
    for (int cf = 0; cf < 4; ++cf) {
        int a = w * 64 + cf * 16 + c16;
        hreg[cf] = h[b * ATTSZ + a] + wv_b[a];
        wreg[cf] = wa[a];
    }
    float pv[8][4];
#pragma unroll
    for (int m = 0; m < 8; ++m)
#pragma unroll
        for (int j = 0; j < 4; ++j) pv[m][j] = 0.f;
#pragma unroll
    for (int m = 0; m < 8; ++m)
#pragma unroll
        for (int cf = 0; cf < 4; ++cf)
#pragma unroll
            for (int j = 0; j < 4; ++j)
                pv[m][j] += tanhf(acc[m][cf][j] + hreg[cf]) * wreg[cf];
#pragma unroll
    for (int m = 0; m < 8; ++m)
#pragma unroll
        for (int j = 0; j < 4; ++j) {
            float v = pv[m][j];
            v += __shfl_xor(v, 1); v += __shfl_xor(v, 2);
            v += __shfl_xor(v, 4); v += __shfl_xor(v, 8);
            pv[m][j] = v;
        }
    float* scp = (float*)smem;   // alias A bufs (loop ended with barrier)
    __syncthreads();
    if (c16 == 0) {
#pragma unroll
        for (int m = 0; m < 8; ++m)
#pragma unroll
            for (int j = 0; j < 4; ++j)
                scp[w * 128 + m * 16 + q4 * 4 + j] = pv[m][j];
    }
    __syncthreads();
    if (t < 128) {
        float s = 0.f;
#pragma unroll
        for (int ww = 0; ww < 8; ++ww) s += scp[ww * 128 + t];
        scores[m0 + t] = s;
    }
}

// ---------------- K2: softmax over N=512 per batch ----------------
__global__ void k_softmax(const float* __restrict__ scores, float* __restrict__ alpha) {
    __shared__ float red[16];
    const int b = blockIdx.x, t = threadIdx.x;     // 512 threads
    const int lane = t & 63, w = t >> 6;
    float s = scores[b * FEATN + t];
    float m = s;
#pragma unroll
    for (int d = 32; d; d >>= 1) m = fmaxf(m, __shfl_xor(m, d));
    if (lane == 0) red[w] = m;
    __syncthreads();
    if (t == 0) {
        float mm = red[0];
        for (int i = 1; i < 8; ++i) mm = fmaxf(mm, red[i]);
        red[8] = mm;
    }
    __syncthreads();
    float e = __expf(s - red[8]);
    float sum = e;
#pragma unroll
    for (int d = 32; d; d >>= 1) sum += __shfl_xor(sum, d);
    if (lane == 0) red[w] = sum;
    __syncthreads();
    if (t == 0) {
        float ss = 0.f;
        for (int i = 0; i < 8; ++i) ss += red[i];
        red[9] = 1.0f / ss;
    }
    __syncthreads();
    alpha[b * FEATN + t] = e * red[9];
}

// ---------------- K3a: partial att_feats over n-slices ----------------
__global__ void k_att_part(const float* __restrict__ feats, const float* __restrict__ alpha,
                           float* __restrict__ part) {
    const int b = blockIdx.x, fc = blockIdx.y, ns = blockIdx.z, t = threadIdx.x;
    const int f0 = fc * 1024 + t * 4;
    const float* fp = feats + (size_t)(b * FEATN + ns * 128) * FEATSZ + f0;
    const float* al = alpha + b * FEATN + ns * 128;
    float4 acc = {0.f, 0.f, 0.f, 0.f};
#pragma unroll 4
    for (int i = 0; i < 128; ++i) {
        float a = al[i];
        float4 v = *(const float4*)(fp + (size_t)i * FEATSZ);
        acc.x += a * v.x; acc.y += a * v.y; acc.z += a * v.z; acc.w += a * v.w;
    }
    *(float4*)(part + ((size_t)ns * BATCH + b) * FEATSZ + f0) = acc;
}

// ---------------- K3b: reduce 4 partials -> att_feats ----------------
__global__ void k_att_red(const float* __restrict__ part, float* __restrict__ out) {
    const int idx = (blockIdx.x * 256 + threadIdx.x) * 4;   // < 131072
    float4 s = *(const float4*)(part + idx);
#pragma unroll
    for (int z = 1; z < 4; ++z) {
        float4 v = *(const float4*)(part + (size_t)z * (BATCH * FEATSZ) + idx);
        s.x += v.x; s.y += v.y; s.z += v.z; s.w += v.w;
    }
    *(float4*)(out + idx) = s;
}

extern "C" void kernel_launch(void* const* d_in, const int* in_sizes, int n_in,
                              void* d_out, int out_size, void* d_ws, size_t ws_size,
                              hipStream_t stream) {
    const float* feats = (const float*)d_in[0];
    const float* key   = (const float*)d_in[1];
    const float* wh_w  = (const float*)d_in[2];
    const float* wh_b  = (const float*)d_in[3];
    const float* wv_w  = (const float*)d_in[4];
    const float* wv_b  = (const float*)d_in[5];
    const float* wa_w  = (const float*)d_in[6];

    float* out_att   = (float*)d_out;                 // 64*2048
    float* out_alpha = out_att + BATCH * FEATSZ;      // 64*512

    char* ws = (char*)d_ws;
    float* h            = (float*)(ws);               // 128 KB
    float* scores       = (float*)(ws + 131072);      // 128 KB
    unsigned short* wvb = (unsigned short*)(ws + 262144);  // 2 MB
    float* part         = (float*)(ws + 262144);      // 2 MB (reuses wvb after K1)

    hipLaunchKernelGGL(k_h,        dim3(8, 64),    dim3(256), 0, stream, key, wh_w, wh_b, h);
    hipLaunchKernelGGL(k_wvcvt,    dim3(4096),     dim3(256), 0, stream, wv_w, wvb);
    hipLaunchKernelGGL(k_scores,   dim3(256),      dim3(512), 0, stream, feats, wvb, h, wv_b, wa_w, scores);
    hipLaunchKernelGGL(k_softmax,  dim3(64),       dim3(512), 0, stream, scores, out_alpha);
    hipLaunchKernelGGL(k_att_part, dim3(64, 2, 4), dim3(256), 0, stream, feats, out_alpha, part);
    hipLaunchKernelGGL(k_att_red,  dim3(128),      dim3(256), 0, stream, part, out_att);
}